// Round 22
// baseline (619.880 us; speedup 1.0000x reference)
//
#include <hip/hip_runtime.h>
#include <hip/hip_bf16.h>
#include <stdint.h>

#define H 256
#define G 4096
#define TK 32     // k1a tile rows
#define TP0 128   // k0 / fallback k1b tile rows
#define TPB 512   // k1b_q8 tile rows

typedef __attribute__((ext_vector_type(8))) short bf16x8;
typedef __attribute__((ext_vector_type(4))) float f32x4;
typedef __attribute__((ext_vector_type(2))) float f32x2;

__device__ inline short f2bf(float f){
  union { float f; uint32_t u; } v; v.f = f;
  uint32_t r = (v.u + 0x7FFFu + ((v.u >> 16) & 1u)) >> 16;
  return (short)(uint16_t)r;
}
__device__ inline float bf2f(short s){
  union { float f; uint32_t u; } v; v.u = ((uint32_t)(uint16_t)s) << 16;
  return v.f;
}
__device__ inline uint32_t pk2(float lo, float hi){
  return (uint32_t)(uint16_t)f2bf(lo) | ((uint32_t)(uint16_t)f2bf(hi) << 16);
}
__device__ inline uint32_t pkfp8(float4 v){
  int u = __builtin_amdgcn_cvt_pk_fp8_f32(v.x, v.y, 0, false);
  u = __builtin_amdgcn_cvt_pk_fp8_f32(v.z, v.w, u, true);
  return (uint32_t)u;
}
__device__ inline float sigmoidf_(float x){ return 1.f / (1.f + __expf(-x)); }

// LDS-only barrier: does NOT drain vmcnt, so in-flight global loads continue.
__device__ inline void ldsbar(){
  asm volatile("s_waitcnt lgkmcnt(0)" ::: "memory");
  __builtin_amdgcn_s_barrier();
}

// ---------------- conv_w: weight conversions + zero counts/pool ----------------
__global__ void conv_w(const float* __restrict__ w1, const float* __restrict__ wih,
                       const float* __restrict__ whh,
                       short* __restrict__ o1, short* __restrict__ oih, short* __restrict__ ohh,
                       uint8_t* __restrict__ w1q,
                       float* __restrict__ counts, float* __restrict__ pool){
  int i = blockIdx.x * 256 + threadIdx.x;
  if (i < H*H) o1[i] = f2bf(w1[i]);
  if (i < 3*H*H){ oih[i] = f2bf(wih[i]); ohh[i] = f2bf(whh[i]); }
  if (i < H*H/4){
    float4 v = *(const float4*)(w1 + (size_t)i*4);
    *(uint32_t*)(w1q + (size_t)i*4) = pkfp8(v);
  }
  if (i < G) counts[i] = 0.f;
  for (int j = i; j < G*H; j += 768*256) pool[j] = 0.f;
}

// ---------------- K0: mean-pool + counts + write x_fp8 + zero sgate ----------------
__global__ __launch_bounds__(512) __attribute__((amdgpu_waves_per_eu(2, 8)))
void k0_pool(const float* __restrict__ x, const int* __restrict__ batch,
             float* __restrict__ pool, float* __restrict__ counts,
             uint8_t* __restrict__ xq, float* __restrict__ sgate, int nNodes){
  __shared__ int   ng[TP0];
  __shared__ float Pacc[8][H];
  __shared__ float Cacc[8];
  __shared__ int   spanSh;

  const int t = threadIdx.x;
  const int base = blockIdx.x * TP0;
  const int c4 = (t & 63) * 4;
  const int r0 = (t >> 6) * 16;   // 8 row-groups of 16 rows

  float4 v[16];
  #pragma unroll
  for (int i = 0; i < 16; ++i){
    int node = base + r0 + i;
    if (node < nNodes) v[i] = *(const float4*)(x + (size_t)node*H + c4);
    else v[i] = make_float4(0.f,0.f,0.f,0.f);
  }

  { int gi = blockIdx.x * 512 + t; if (gi < nNodes) sgate[gi] = 0.f; }

  if (t < TP0) ng[t] = (base + t < nNodes) ? batch[base + t] : -1;
  for (int u = t; u < 8*H; u += 512) ((float*)Pacc)[u] = 0.f;
  if (t < 8) Cacc[t] = 0.f;
  __syncthreads();

  if (t == 0){
    int lg = ng[0];
    if (base + TP0 <= nNodes) lg = ng[TP0-1];
    else { for (int i = TP0-1; i > 0; --i){ if (ng[i] >= 0){ lg = ng[i]; break; } } }
    spanSh = (ng[0] >= 0) ? (lg - ng[0]) : -1;
  }

  if (xq){
    #pragma unroll
    for (int i = 0; i < 16; ++i){
      int node = base + r0 + i;
      if (node < nNodes)
        *(uint32_t*)(xq + (size_t)node*H + c4) = pkfp8(v[i]);
    }
  }
  __syncthreads();

  const int g0 = ng[0];
  const bool useLds = (spanSh >= 0) && (spanSh < 8);

  float ax=0.f, ay=0.f, az=0.f, aw=0.f;
  int cur = ng[r0];
  if (cur >= 0){
    #pragma unroll
    for (int i = 0; i < 16; ++i){
      int g = ng[r0 + i];
      if (g < 0) break;
      if (g != cur){
        if (useLds){
          atomicAdd(&Pacc[cur-g0][c4], ax);   atomicAdd(&Pacc[cur-g0][c4+1], ay);
          atomicAdd(&Pacc[cur-g0][c4+2], az); atomicAdd(&Pacc[cur-g0][c4+3], aw);
        } else {
          atomicAdd(&pool[(size_t)cur*H + c4], ax);   atomicAdd(&pool[(size_t)cur*H + c4+1], ay);
          atomicAdd(&pool[(size_t)cur*H + c4+2], az); atomicAdd(&pool[(size_t)cur*H + c4+3], aw);
        }
        ax=ay=az=aw=0.f; cur = g;
      }
      ax += v[i].x; ay += v[i].y; az += v[i].z; aw += v[i].w;
    }
    if (useLds){
      atomicAdd(&Pacc[cur-g0][c4], ax);   atomicAdd(&Pacc[cur-g0][c4+1], ay);
      atomicAdd(&Pacc[cur-g0][c4+2], az); atomicAdd(&Pacc[cur-g0][c4+3], aw);
    } else {
      atomicAdd(&pool[(size_t)cur*H + c4], ax);   atomicAdd(&pool[(size_t)cur*H + c4+1], ay);
      atomicAdd(&pool[(size_t)cur*H + c4+2], az); atomicAdd(&pool[(size_t)cur*H + c4+3], aw);
    }
  }
  if (t < TP0 && ng[t] >= 0){
    if (useLds) atomicAdd(&Cacc[ng[t]-g0], 1.f);
    else        atomicAdd(&counts[ng[t]], 1.f);
  }
  __syncthreads();

  if (useLds){
    int nr = spanSh + 1;
    for (int u = t; u < nr*H; u += 512){
      int r = u >> 8, c = u & 255;
      float vv = Pacc[r][c];
      if (vv != 0.f) atomicAdd(&pool[(size_t)(g0+r)*H + c], vv);
    }
    if (t < nr && Cacc[t] != 0.f) atomicAdd(&counts[g0 + t], Cacc[t]);
  }
}

// ---------------- KT2: repr = pool/cnt; zero pool; hgp GEMM ----------------
__global__ __launch_bounds__(256) void kT2(float* __restrict__ pool,
    const float* __restrict__ counts, float* __restrict__ repr,
    const short* __restrict__ w1bf, const float* __restrict__ b1,
    uint32_t* __restrict__ hgp){
  __shared__ short Ar[16][H + 8];
  const int t    = threadIdx.x;
  const int wid  = t >> 6;
  const int lane = t & 63;
  const int l15  = lane & 15;
  const int l4   = lane >> 4;
  const int g0   = blockIdx.x * 16;

  for (int u = t; u < 16*32; u += 256){
    int row = u >> 5, cg = u & 31;
    int c0 = cg * 8;
    int g = g0 + row;
    float cnt = fmaxf(counts[g], 1.f);
    float4* pp = (float4*)(pool + (size_t)g*H + c0);
    float4 p0 = pp[0], p1 = pp[1];
    p0.x/=cnt; p0.y/=cnt; p0.z/=cnt; p0.w/=cnt;
    p1.x/=cnt; p1.y/=cnt; p1.z/=cnt; p1.w/=cnt;
    float4* rp = (float4*)(repr + (size_t)g*H + c0);
    rp[0] = p0; rp[1] = p1;
    pp[0] = make_float4(0.f,0.f,0.f,0.f);
    pp[1] = make_float4(0.f,0.f,0.f,0.f);
    bf16x8 o;
    o[0]=f2bf(p0.x); o[1]=f2bf(p0.y); o[2]=f2bf(p0.z); o[3]=f2bf(p0.w);
    o[4]=f2bf(p1.x); o[5]=f2bf(p1.y); o[6]=f2bf(p1.z); o[7]=f2bf(p1.w);
    *(bf16x8*)(&Ar[row][c0]) = o;
  }
  __syncthreads();

  f32x4 acc[4];
  #pragma unroll
  for (int i = 0; i < 4; ++i) acc[i] = (f32x4){0.f,0.f,0.f,0.f};
  #pragma unroll
  for (int kc = 0; kc < 8; ++kc){
    bf16x8 a = *(bf16x8*)(&Ar[l15][kc*32 + l4*8]);
    #pragma unroll
    for (int nt = 0; nt < 4; ++nt){
      int col = wid*64 + nt*16 + l15;
      bf16x8 b = *(const bf16x8*)(w1bf + (size_t)col*H + kc*32 + l4*8);
      acc[nt] = __builtin_amdgcn_mfma_f32_16x16x32_bf16(a, b, acc[nt], 0, 0, 0);
    }
  }
  const float b1v0 = b1[wid*64 + l15];
  const float b1v1 = b1[wid*64 + 16 + l15];
  const float b1v2 = b1[wid*64 + 32 + l15];
  const float b1v3 = b1[wid*64 + 48 + l15];
  #pragma unroll
  for (int j = 0; j < 4; ++j){
    int row = l4*4 + j;
    hgp[(size_t)(g0+row)*128 + wid*32 + l15]      = pk2(acc[0][j]+b1v0, acc[1][j]+b1v1);
    hgp[(size_t)(g0+row)*128 + wid*32 + 16 + l15] = pk2(acc[2][j]+b1v2, acc[3][j]+b1v3);
  }
}

// ---------------- K1a-fp8: gate scores, FULL-COL persistent GEMM ----------------
// __launch_bounds__(256,4): pin allocator to 128 VGPR -> guaranteed 4 blocks/CU.
__global__ __launch_bounds__(256, 4)
void k1a_fp8(
    const uint8_t* __restrict__ xq, const int* __restrict__ batch,
    const uint32_t* __restrict__ hgp, const uint8_t* __restrict__ w1q,
    const float* __restrict__ w2, float* __restrict__ sgate,
    int nNodes, int nTiles, int nBlk){

  __shared__ uint8_t Ain[2][TK][H + 16];   // 272B pitch, 17.4 KB
  __shared__ int     ngS[2][TK];

  const int t    = threadIdx.x;
  const int wid  = t >> 6;      // 0..3 -> cols wid*64 .. wid*64+64
  const int lane = t & 63;
  const int l15  = lane & 15;
  const int l4   = lane >> 4;
  const int colB = wid*64;

  const int tile0 = (int)(((long long)blockIdx.x * nTiles) / nBlk);
  const int tile1 = (int)(((long long)(blockIdx.x+1) * nTiles) / nBlk);
  if (tile0 >= tile1) return;

  long BfA0[8], BfA1[8], BfB0[8], BfB1[8];
  {
    const uint8_t* wp = w1q + (size_t)(colB + l15)*H + l4*8;
    #pragma unroll
    for (int kc = 0; kc < 8; ++kc){
      BfA0[kc] = *(const long*)(wp + kc*32);
      BfA1[kc] = *(const long*)(wp + 16*H + kc*32);
      BfB0[kc] = *(const long*)(wp + 32*H + kc*32);
      BfB1[kc] = *(const long*)(wp + 48*H + kc*32);
    }
  }
  const float w2A0 = w2[colB + l15];
  const float w2A1 = w2[colB + 16 + l15];
  const float w2B0 = w2[colB + 32 + l15];
  const float w2B1 = w2[colB + 48 + l15];

  const int srow  = t >> 4;        // 0..15
  const int scolB = (t & 15) * 16; // byte offset
  uint4 xv0, xv1;
  int ngv = -1;

  auto issueT = [&](int tile){
    int base = tile * TK;
    int n0 = base + srow, n1 = n0 + 16;
    xv0 = (n0 < nNodes) ? *(const uint4*)(xq + (size_t)n0*H + scolB) : make_uint4(0,0,0,0);
    xv1 = (n1 < nNodes) ? *(const uint4*)(xq + (size_t)n1*H + scolB) : make_uint4(0,0,0,0);
    if (t < TK){
      int node = base + t;
      ngv = (node < nNodes) ? batch[node] : -1;
    }
  };
  auto stageT = [&](int buf){
    *(uint4*)(&Ain[buf][srow][scolB])      = xv0;
    *(uint4*)(&Ain[buf][srow + 16][scolB]) = xv1;
    if (t < TK) ngS[buf][t] = ngv;
  };

  issueT(tile0);
  stageT(0);
  if (tile0 + 1 < tile1) issueT(tile0 + 1);

  int cur = 0;
  for (int tile = tile0; tile < tile1; ++tile, cur ^= 1){
    ldsbar();

    // ---- group A: cols colB..colB+32 ----
    uint32_t hvp[2][4];
    #pragma unroll
    for (int r = 0; r < 2; ++r)
      #pragma unroll
      for (int j = 0; j < 4; ++j){
        int g = ngS[cur][r*16 + l4*4 + j];
        hvp[r][j] = (g >= 0) ? hgp[(size_t)g*128 + wid*32 + l15] : 0u;
      }

    f32x4 acc0[2], acc1[2];
    #pragma unroll
    for (int r = 0; r < 2; ++r){ acc0[r] = (f32x4){0.f,0.f,0.f,0.f}; acc1[r] = (f32x4){0.f,0.f,0.f,0.f}; }
    #pragma unroll
    for (int kc = 0; kc < 8; ++kc){
      #pragma unroll
      for (int r = 0; r < 2; ++r){
        long a = *(const long*)(&Ain[cur][r*16 + l15][kc*32 + l4*8]);
        acc0[r] = __builtin_amdgcn_mfma_f32_16x16x32_fp8_fp8(a, BfA0[kc], acc0[r], 0, 0, 0);
        acc1[r] = __builtin_amdgcn_mfma_f32_16x16x32_fp8_fp8(a, BfA1[kc], acc1[r], 0, 0, 0);
      }
    }

    if (tile + 1 < tile1){
      stageT(cur ^ 1);
      if (tile + 2 < tile1) issueT(tile + 2);
    }

    float p[2][4];
    #pragma unroll
    for (int r = 0; r < 2; ++r)
      #pragma unroll
      for (int j = 0; j < 4; ++j){
        float h0 = fmaxf(acc0[r][j] + bf2f((short)(uint16_t)(hvp[r][j] & 0xFFFFu)), 0.f);
        float h1 = fmaxf(acc1[r][j] + bf2f((short)(uint16_t)(hvp[r][j] >> 16)), 0.f);
        p[r][j] = w2A0*h0 + w2A1*h1;
      }

    // ---- group B: cols colB+32..colB+64 ----
    #pragma unroll
    for (int r = 0; r < 2; ++r)
      #pragma unroll
      for (int j = 0; j < 4; ++j){
        int g = ngS[cur][r*16 + l4*4 + j];
        hvp[r][j] = (g >= 0) ? hgp[(size_t)g*128 + wid*32 + 16 + l15] : 0u;
      }
    #pragma unroll
    for (int r = 0; r < 2; ++r){ acc0[r] = (f32x4){0.f,0.f,0.f,0.f}; acc1[r] = (f32x4){0.f,0.f,0.f,0.f}; }
    #pragma unroll
    for (int kc = 0; kc < 8; ++kc){
      #pragma unroll
      for (int r = 0; r < 2; ++r){
        long a = *(const long*)(&Ain[cur][r*16 + l15][kc*32 + l4*8]);
        acc0[r] = __builtin_amdgcn_mfma_f32_16x16x32_fp8_fp8(a, BfB0[kc], acc0[r], 0, 0, 0);
        acc1[r] = __builtin_amdgcn_mfma_f32_16x16x32_fp8_fp8(a, BfB1[kc], acc1[r], 0, 0, 0);
      }
    }
    #pragma unroll
    for (int r = 0; r < 2; ++r)
      #pragma unroll
      for (int j = 0; j < 4; ++j){
        float h0 = fmaxf(acc0[r][j] + bf2f((short)(uint16_t)(hvp[r][j] & 0xFFFFu)), 0.f);
        float h1 = fmaxf(acc1[r][j] + bf2f((short)(uint16_t)(hvp[r][j] >> 16)), 0.f);
        p[r][j] += w2B0*h0 + w2B1*h1;
      }

    #pragma unroll
    for (int off = 1; off < 16; off <<= 1){
      #pragma unroll
      for (int r = 0; r < 2; ++r)
        #pragma unroll
        for (int j = 0; j < 4; ++j) p[r][j] += __shfl_xor(p[r][j], off);
    }
    if (l15 == 0){
      int base = tile * TK;
      #pragma unroll
      for (int r = 0; r < 2; ++r)
        #pragma unroll
        for (int j = 0; j < 4; ++j){
          int idx = r*16 + l4*4 + j;
          if (ngS[cur][idx] >= 0)
            atomicAdd(&sgate[base + idx], p[r][j]);
        }
    }
  }
}

// ---------------- K1b-q8: streaming pooling from fp8 x, 512-row tiles; zeroes sgate ----------------
__global__ __launch_bounds__(512) __attribute__((amdgpu_waves_per_eu(2, 8)))
void k1b_q8(
    const uint8_t* __restrict__ xq, const int* __restrict__ batch,
    float* __restrict__ sgate, const float* __restrict__ b2p,
    float* __restrict__ pool, int nNodes){

  __shared__ int   ng[TPB];
  __shared__ float gs[TPB];
  __shared__ float Pacc[16][H];
  __shared__ int   spanSh;

  const int t = threadIdx.x;
  const int base = blockIdx.x * TPB;
  const int c4 = (t & 63) * 4;
  const int r0 = (t >> 6) * 64;   // 8 row-groups of 64 rows

  // 64 x 4B = 256 B/thread in flight
  uint32_t u[64];
  #pragma unroll
  for (int i = 0; i < 64; ++i){
    int node = base + r0 + i;
    u[i] = (node < nNodes) ? *(const uint32_t*)(xq + (size_t)node*H + c4) : 0u;
  }

  const float b2v = b2p[0];
  {
    int node = base + t;
    if (node < nNodes){
      ng[t] = batch[node];
      gs[t] = sigmoidf_(sgate[node] + b2v);
      sgate[node] = 0.f;               // ready for next k1a pass
    } else { ng[t] = -1; gs[t] = 0.f; }
  }
  for (int w = t; w < 16*H; w += 512) ((float*)Pacc)[w] = 0.f;
  __syncthreads();

  if (t == 0){
    int lg = ng[0];
    if (base + TPB <= nNodes) lg = ng[TPB-1];
    else { for (int i = TPB-1; i > 0; --i){ if (ng[i] >= 0){ lg = ng[i]; break; } } }
    spanSh = (ng[0] >= 0) ? (lg - ng[0]) : -1;
  }
  __syncthreads();

  const int g0 = ng[0];
  const bool useLds = (spanSh >= 0) && (spanSh < 16);

  float ax=0.f, ay=0.f, az=0.f, aw=0.f;
  int cur = ng[r0];
  if (cur >= 0){
    #pragma unroll
    for (int i = 0; i < 64; ++i){
      int g = ng[r0 + i];
      if (g < 0) break;
      if (g != cur){
        if (useLds){
          atomicAdd(&Pacc[cur-g0][c4], ax);   atomicAdd(&Pacc[cur-g0][c4+1], ay);
          atomicAdd(&Pacc[cur-g0][c4+2], az); atomicAdd(&Pacc[cur-g0][c4+3], aw);
        } else {
          atomicAdd(&pool[(size_t)cur*H + c4], ax);   atomicAdd(&pool[(size_t)cur*H + c4+1], ay);
          atomicAdd(&pool[(size_t)cur*H + c4+2], az); atomicAdd(&pool[(size_t)cur*H + c4+3], aw);
        }
        ax=ay=az=aw=0.f; cur = g;
      }
      float gv = gs[r0 + i];
      f32x2 lo = __builtin_amdgcn_cvt_pk_f32_fp8((int)u[i], false);
      f32x2 hi = __builtin_amdgcn_cvt_pk_f32_fp8((int)u[i], true);
      ax += gv * lo[0]; ay += gv * lo[1];
      az += gv * hi[0]; aw += gv * hi[1];
    }
    if (useLds){
      atomicAdd(&Pacc[cur-g0][c4], ax);   atomicAdd(&Pacc[cur-g0][c4+1], ay);
      atomicAdd(&Pacc[cur-g0][c4+2], az); atomicAdd(&Pacc[cur-g0][c4+3], aw);
    } else {
      atomicAdd(&pool[(size_t)cur*H + c4], ax);   atomicAdd(&pool[(size_t)cur*H + c4+1], ay);
      atomicAdd(&pool[(size_t)cur*H + c4+2], az); atomicAdd(&pool[(size_t)cur*H + c4+3], aw);
    }
  }
  __syncthreads();

  if (useLds){
    int nr = spanSh + 1;
    for (int w = t; w < nr*H; w += 512){
      int r = w >> 8, c = w & 255;
      float vv = Pacc[r][c];
      if (vv != 0.f) atomicAdd(&pool[(size_t)(g0+r)*H + c], vv);
    }
  }
}

// ---------------- fallback path (small ws): bf16 col-half GEMM + f32 pooling ----------------
__global__ __launch_bounds__(256) __attribute__((amdgpu_waves_per_eu(3, 4)))
void k1a_gate_f32(
    const float* __restrict__ xf32, const int* __restrict__ batch,
    const uint32_t* __restrict__ hgp, const short* __restrict__ w1bf,
    const float* __restrict__ w2, float* __restrict__ sgate,
    int nNodes, int nTiles, int nChains){

  __shared__ short Ain[2][TK][H + 8];
  __shared__ int   ngS[2][TK];

  const int t    = threadIdx.x;
  const int wid  = t >> 6;
  const int lane = t & 63;
  const int l15  = lane & 15;
  const int l4   = lane >> 4;

  const int ch    = blockIdx.x >= nChains;
  const int chain = ch ? blockIdx.x - nChains : blockIdx.x;
  const int colB  = ch*128 + wid*32;
  const int hgcol = ch*64 + wid*16 + l15;

  const int tile0 = (int)(((long long)chain * nTiles) / nChains);
  const int tile1 = (int)(((long long)(chain+1) * nTiles) / nChains);
  if (tile0 >= tile1) return;

  bf16x8 Bf0[8], Bf1[8];
  {
    const short* wp0 = w1bf + (size_t)(colB + l15)*H + l4*8;
    #pragma unroll
    for (int kc = 0; kc < 8; ++kc){
      Bf0[kc] = *(const bf16x8*)(wp0 + kc*32);
      Bf1[kc] = *(const bf16x8*)(wp0 + 16*H + kc*32);
    }
  }
  const float w2v0 = w2[colB + l15];
  const float w2v1 = w2[colB + 16 + l15];

  const int srow = t >> 5;
  const int scol = (t & 31) * 8;
  float4 xf[4][2];
  int ngv = -1;

  auto issueT = [&](int tile){
    int base = tile * TK;
    #pragma unroll
    for (int q = 0; q < 4; ++q){
      int node = base + srow + q*8;
      if (node < nNodes){
        const float4* xp = (const float4*)(xf32 + (size_t)node*H + scol);
        xf[q][0] = xp[0]; xf[q][1] = xp[1];
      } else { xf[q][0] = make_float4(0.f,0.f,0.f,0.f); xf[q][1] = make_float4(0.f,0.f,0.f,0.f); }
    }
    if (t < TK){
      int node = base + t;
      ngv = (node < nNodes) ? batch[node] : -1;
    }
  };
  auto stageT = [&](int buf){
    #pragma unroll
    for (int q = 0; q < 4; ++q){
      bf16x8 o;
      float4 a = xf[q][0], c = xf[q][1];
      o[0]=f2bf(a.x); o[1]=f2bf(a.y); o[2]=f2bf(a.z); o[3]=f2bf(a.w);
      o[4]=f2bf(c.x); o[5]=f2bf(c.y); o[6]=f2bf(c.z); o[7]=f2bf(c.w);
      *(bf16x8*)(&Ain[buf][srow + q*8][scol]) = o;
    }
    if (t < TK) ngS[buf][t] = ngv;
  };

  issueT(tile0);
  stageT(0);
  if (tile0 + 1 < tile1) issueT(tile0 + 1);

  int cur = 0;
  for (int tile = tile0; tile < tile1; ++tile, cur ^= 1){
    ldsbar();

    int gr[2][4];
    uint32_t hvp[2][4];
    #pragma unroll
    for (int r = 0; r < 2; ++r)
      #pragma unroll
      for (int j = 0; j < 4; ++j){
        int g = ngS[cur][r*16 + l4*4 + j];
        gr[r][j] = g;
        hvp[r][j] = (g >= 0) ? hgp[(size_t)g*128 + hgcol] : 0u;
      }

    f32x4 acc0[2], acc1[2];
    #pragma unroll
    for (int r = 0; r < 2; ++r){ acc0[r] = (f32x4){0.f,0.f,0.f,0.f}; acc1[r] = (f32x4){0.f,0.f,0.f,0.f}; }
    #pragma unroll
    for (int kc = 0; kc < 8; ++kc){
      #pragma unroll
      for (int r = 0; r < 2; ++r){
        bf16x8 a = *(bf16x8*)(&Ain[cur][r*16 + l15][kc*32 + l4*8]);
        acc0[r] = __builtin_amdgcn_mfma_f32_16x16x32_bf16(a, Bf0[kc], acc0[r], 0, 0, 0);
        acc1[r] = __builtin_amdgcn_mfma_f32_16x16x32_bf16(a, Bf1[kc], acc1[r], 0, 0, 0);
      }
    }

    if (tile + 1 < tile1){
      stageT(cur ^ 1);
      if (tile + 2 < tile1) issueT(tile + 2);
    }

    float p[2][4];
    #pragma unroll
    for (int r = 0; r < 2; ++r)
      #pragma unroll
      for (int j = 0; j < 4; ++j){
        float h0 = fmaxf(acc0[r][j] + bf2f((short)(uint16_t)(hvp[r][j] & 0xFFFFu)), 0.f);
        float h1 = fmaxf(acc1[r][j] + bf2f((short)(uint16_t)(hvp[r][j] >> 16)), 0.f);
        p[r][j] = w2v0*h0 + w2v1*h1;
      }
    #pragma unroll
    for (int off = 1; off < 16; off <<= 1){
      #pragma unroll
      for (int r = 0; r < 2; ++r)
        #pragma unroll
        for (int j = 0; j < 4; ++j) p[r][j] += __shfl_xor(p[r][j], off);
    }
    if (l15 == 0){
      int base = tile * TK;
      #pragma unroll
      for (int r = 0; r < 2; ++r)
        #pragma unroll
        for (int j = 0; j < 4; ++j){
          if (gr[r][j] >= 0)
            atomicAdd(&sgate[base + r*16 + l4*4 + j], p[r][j]);
        }
    }
  }
}

__global__ __launch_bounds__(512) __attribute__((amdgpu_waves_per_eu(2, 8)))
void k1b_f32(
    const float* __restrict__ xf32, const int* __restrict__ batch,
    float* __restrict__ sgate, const float* __restrict__ b2p,
    float* __restrict__ pool, int nNodes){

  __shared__ int   ng[TP0];
  __shared__ float gs[TP0];
  __shared__ float Pacc[8][H];
  __shared__ int   spanSh;

  const int t = threadIdx.x;
  const int base = blockIdx.x * TP0;
  const int c4 = (t & 63) * 4;
  const int r0 = (t >> 6) * 16;

  float4 vf[16];
  #pragma unroll
  for (int i = 0; i < 16; ++i){
    int node = base + r0 + i;
    vf[i] = (node < nNodes) ? *(const float4*)(xf32 + (size_t)node*H + c4)
                            : make_float4(0.f,0.f,0.f,0.f);
  }

  const float b2v = b2p[0];
  if (t < TP0){
    int node = base + t;
    if (node < nNodes){
      ng[t] = batch[node];
      gs[t] = sigmoidf_(sgate[node] + b2v);
      sgate[node] = 0.f;
    } else { ng[t] = -1; gs[t] = 0.f; }
  }
  for (int w = t; w < 8*H; w += 512) ((float*)Pacc)[w] = 0.f;
  __syncthreads();

  if (t == 0){
    int lg = ng[0];
    if (base + TP0 <= nNodes) lg = ng[TP0-1];
    else { for (int i = TP0-1; i > 0; --i){ if (ng[i] >= 0){ lg = ng[i]; break; } } }
    spanSh = (ng[0] >= 0) ? (lg - ng[0]) : -1;
  }
  __syncthreads();

  const int g0 = ng[0];
  const bool useLds = (spanSh >= 0) && (spanSh < 8);

  float ax=0.f, ay=0.f, az=0.f, aw=0.f;
  int cur = ng[r0];
  if (cur >= 0){
    #pragma unroll
    for (int i = 0; i < 16; ++i){
      int g = ng[r0 + i];
      if (g < 0) break;
      if (g != cur){
        if (useLds){
          atomicAdd(&Pacc[cur-g0][c4], ax);   atomicAdd(&Pacc[cur-g0][c4+1], ay);
          atomicAdd(&Pacc[cur-g0][c4+2], az); atomicAdd(&Pacc[cur-g0][c4+3], aw);
        } else {
          atomicAdd(&pool[(size_t)cur*H + c4], ax);   atomicAdd(&pool[(size_t)cur*H + c4+1], ay);
          atomicAdd(&pool[(size_t)cur*H + c4+2], az); atomicAdd(&pool[(size_t)cur*H + c4+3], aw);
        }
        ax=ay=az=aw=0.f; cur = g;
      }
      float gv = gs[r0 + i];
      ax += gv * bf2f(f2bf(vf[i].x)); ay += gv * bf2f(f2bf(vf[i].y));
      az += gv * bf2f(f2bf(vf[i].z)); aw += gv * bf2f(f2bf(vf[i].w));
    }
    if (useLds){
      atomicAdd(&Pacc[cur-g0][c4], ax);   atomicAdd(&Pacc[cur-g0][c4+1], ay);
      atomicAdd(&Pacc[cur-g0][c4+2], az); atomicAdd(&Pacc[cur-g0][c4+3], aw);
    } else {
      atomicAdd(&pool[(size_t)cur*H + c4], ax);   atomicAdd(&pool[(size_t)cur*H + c4+1], ay);
      atomicAdd(&pool[(size_t)cur*H + c4+2], az); atomicAdd(&pool[(size_t)cur*H + c4+3], aw);
    }
  }
  __syncthreads();

  if (useLds){
    int nr = spanSh + 1;
    for (int w = t; w < nr*H; w += 512){
      int r = w >> 8, c = w & 255;
      float vv = Pacc[r][c];
      if (vv != 0.f) atomicAdd(&pool[(size_t)(g0+r)*H + c], vv);
    }
  }
}

// ---------------- K2: fused GRU (+ optional hgp for next ts); zeroes pool ----------------
__global__ __launch_bounds__(256) void k2_gru(float* __restrict__ pool,
    const float* __restrict__ counts, const float* __restrict__ repr_in,
    const short* __restrict__ wihbf, const short* __restrict__ whhbf,
    const float* __restrict__ bih, const float* __restrict__ bhh,
    float* __restrict__ repr_out,
    const short* __restrict__ w1bf, const float* __restrict__ b1,
    uint32_t* __restrict__ hgp, int doHg){

  __shared__ short Anew[16][H + 8];
  __shared__ short Aold[16][H + 8];
  __shared__ float hold[16][H];
  __shared__ float srz[16][2*H];
  __shared__ float sni[16][H];
  __shared__ float snh[16][H];

  const int t    = threadIdx.x;
  const int wid  = t >> 6;
  const int lane = t & 63;
  const int l15  = lane & 15;
  const int l4   = lane >> 4;
  const int g0   = blockIdx.x * 16;

  for (int u = t; u < 16*H; u += 256){
    int row = u >> 8, c = u & 255;
    int g = g0 + row;
    float cnt = fmaxf(counts[g], 1.f);
    float rin = repr_in[(size_t)g*H + c];
    float nr  = pool[(size_t)g*H + c] / cnt;
    pool[(size_t)g*H + c] = 0.f;
    Anew[row][c] = f2bf(nr);
    Aold[row][c] = f2bf(rin);
    hold[row][c] = rin;
  }
  __syncthreads();

  f32x4 ai[12], ah[12];
  #pragma unroll
  for (int i = 0; i < 12; ++i){ ai[i] = (f32x4){0.f,0.f,0.f,0.f}; ah[i] = (f32x4){0.f,0.f,0.f,0.f}; }

  for (int kc = 0; kc < 8; ++kc){
    bf16x8 an = *(bf16x8*)(&Anew[l15][kc*32 + l4*8]);
    bf16x8 ao = *(bf16x8*)(&Aold[l15][kc*32 + l4*8]);
    #pragma unroll
    for (int nt = 0; nt < 12; ++nt){
      int n = wid*192 + nt*16 + l15;
      bf16x8 bi = *(const bf16x8*)(wihbf + (size_t)n*H + kc*32 + l4*8);
      bf16x8 bh = *(const bf16x8*)(whhbf + (size_t)n*H + kc*32 + l4*8);
      ai[nt] = __builtin_amdgcn_mfma_f32_16x16x32_bf16(an, bi, ai[nt], 0, 0, 0);
      ah[nt] = __builtin_amdgcn_mfma_f32_16x16x32_bf16(ao, bh, ah[nt], 0, 0, 0);
    }
  }

  #pragma unroll
  for (int nt = 0; nt < 12; ++nt){
    int n = wid*192 + nt*16 + l15;
    float bi = bih[n], bh = bhh[n];
    #pragma unroll
    for (int r = 0; r < 4; ++r){
      int row = l4*4 + r;
      float si = ai[nt][r] + bi;
      float sh = ah[nt][r] + bh;
      if (n < 2*H) srz[row][n] = si + sh;
      else { sni[row][n - 2*H] = si; snh[row][n - 2*H] = sh; }
    }
  }
  __syncthreads();

  for (int u = t; u < 16*H; u += 256){
    int row = u >> 8, c = u & 255;
    float rr = sigmoidf_(srz[row][c]);
    float zz = sigmoidf_(srz[row][H + c]);
    float nn = tanhf(sni[row][c] + rr * snh[row][c]);
    float hv = (1.f - zz) * nn + zz * hold[row][c];
    float out = fmaxf(hv, 0.f);
    repr_out[(size_t)(g0 + row)*H + c] = out;
    Anew[row][c] = f2bf(out);
  }

  if (doHg){
    __syncthreads();
    f32x4 acc[4];
    #pragma unroll
    for (int i = 0; i < 4; ++i) acc[i] = (f32x4){0.f,0.f,0.f,0.f};
    #pragma unroll
    for (int kc = 0; kc < 8; ++kc){
      bf16x8 a = *(bf16x8*)(&Anew[l15][kc*32 + l4*8]);
      #pragma unroll
      for (int nt = 0; nt < 4; ++nt){
        int col = wid*64 + nt*16 + l15;
        bf16x8 b = *(const bf16x8*)(w1bf + (size_t)col*H + kc*32 + l4*8);
        acc[nt] = __builtin_amdgcn_mfma_f32_16x16x32_bf16(a, b, acc[nt], 0, 0, 0);
      }
    }
    const float b1v0 = b1[wid*64 + l15];
    const float b1v1 = b1[wid*64 + 16 + l15];
    const float b1v2 = b1[wid*64 + 32 + l15];
    const float b1v3 = b1[wid*64 + 48 + l15];
    #pragma unroll
    for (int j = 0; j < 4; ++j){
      int row = l4*4 + j;
      hgp[(size_t)(g0+row)*128 + wid*32 + l15]      = pk2(acc[0][j]+b1v0, acc[1][j]+b1v1);
      hgp[(size_t)(g0+row)*128 + wid*32 + 16 + l15] = pk2(acc[2][j]+b1v2, acc[3][j]+b1v3);
    }
  }
}

extern "C" void kernel_launch(void* const* d_in, const int* in_sizes, int n_in,
                              void* d_out, int out_size, void* d_ws, size_t ws_size,
                              hipStream_t stream){
  const float* x    = (const float*)d_in[0];
  const float* w1   = (const float*)d_in[1];
  const float* b1   = (const float*)d_in[2];
  const float* w2   = (const float*)d_in[3];
  const float* b2   = (const float*)d_in[4];
  const float* wih  = (const float*)d_in[5];
  const float* whh  = (const float*)d_in[6];
  const float* bih  = (const float*)d_in[7];
  const float* bhh  = (const float*)d_in[8];
  const int*   batch= (const int*)d_in[9];
  const int N = in_sizes[9];

  char* ws = (char*)d_ws;
  short* w1bf   = (short*)(ws + 0);            // 128 KB
  short* wihbf  = (short*)(ws + (1u<<17));     // 384 KB @128K
  short* whhbf  = (short*)(ws + (1u<<19));     // 384 KB @512K
  float* counts = (float*)(ws + 917504);       // 16 KB @896K
  uint8_t* w1q  = (uint8_t*)(ws + 933888);     // 64 KB @912K
  float* pool   = (float*)(ws + (1u<<20));     // 4 MB @1M
  float* repr   = (float*)(ws + (1u<<20) + (1u<<22)); // 4 MB @5M
  float* sgate  = (float*)(ws + (9u<<20));     // 2 MB @9M
  uint32_t* hgp = (uint32_t*)(ws + (12u<<20)); // 2 MB @12M
  float* outp   = (float*)d_out;

  const size_t XQ_OFF = (size_t)16u << 20;     // 16 MB
  const bool useXq = ws_size >= XQ_OFF + (size_t)N * H;  // xq = 128 MB
  uint8_t* xq = useXq ? (uint8_t*)(ws + XQ_OFF) : nullptr;

  const int nTiles32 = (N + TK - 1) / TK;      // 15625
  const int nBlk1a  = 1024;                    // full-col fp8: 4 blocks/CU
  const int nChainsF= 512;                     // fallback bf16 col-half grid
  const int nBlkP   = (N + TP0 - 1) / TP0;     // 3907 (k0, fallback k1b)
  const int nBlkQ   = (N + TPB - 1) / TPB;     // 977 (k1b_q8)

  conv_w<<<768, 256, 0, stream>>>(w1, wih, whh, w1bf, wihbf, whhbf, w1q, counts, pool);
  k0_pool<<<nBlkP, 512, 0, stream>>>(x, batch, pool, counts, xq, sgate, N);
  kT2<<<G/16, 256, 0, stream>>>(pool, counts, repr, w1bf, b1, hgp);

  for (int ts = 0; ts < 2; ++ts){
    if (useXq){
      k1a_fp8<<<nBlk1a, 256, 0, stream>>>(xq, batch, hgp, w1q, w2, sgate, N, nTiles32, nBlk1a);
      k1b_q8<<<nBlkQ, 512, 0, stream>>>(xq, batch, sgate, b2, pool, N);
    } else {
      k1a_gate_f32<<<nChainsF*2, 256, 0, stream>>>(x, batch, hgp, w1bf, w2, sgate, N, nTiles32, nChainsF);
      k1b_f32<<<nBlkP, 512, 0, stream>>>(x, batch, sgate, b2, pool, N);
    }
    k2_gru<<<G/16, 256, 0, stream>>>(pool, counts, repr, wihbf, whhbf, bih, bhh,
                                     (ts == 0) ? repr : outp,
                                     w1bf, b1, hgp, (ts == 0) ? 1 : 0);
  }
}

// Round 23
// 585.694 us; speedup vs baseline: 1.0584x; 1.0584x over previous
//
#include <hip/hip_runtime.h>
#include <hip/hip_bf16.h>
#include <stdint.h>

#define H 256
#define G 4096
#define TK 32     // k1a tile rows
#define TP0 128   // k0 / fallback k1b tile rows
#define TPB 512   // k1b_q8 tile rows

typedef __attribute__((ext_vector_type(8))) short bf16x8;
typedef __attribute__((ext_vector_type(4))) float f32x4;
typedef __attribute__((ext_vector_type(2))) float f32x2;

__device__ inline short f2bf(float f){
  union { float f; uint32_t u; } v; v.f = f;
  uint32_t r = (v.u + 0x7FFFu + ((v.u >> 16) & 1u)) >> 16;
  return (short)(uint16_t)r;
}
__device__ inline float bf2f(short s){
  union { float f; uint32_t u; } v; v.u = ((uint32_t)(uint16_t)s) << 16;
  return v.f;
}
__device__ inline uint32_t pk2(float lo, float hi){
  return (uint32_t)(uint16_t)f2bf(lo) | ((uint32_t)(uint16_t)f2bf(hi) << 16);
}
__device__ inline uint32_t pkfp8(float4 v){
  int u = __builtin_amdgcn_cvt_pk_fp8_f32(v.x, v.y, 0, false);
  u = __builtin_amdgcn_cvt_pk_fp8_f32(v.z, v.w, u, true);
  return (uint32_t)u;
}
__device__ inline float sigmoidf_(float x){ return 1.f / (1.f + __expf(-x)); }

// LDS-only barrier: does NOT drain vmcnt, so in-flight global loads continue.
__device__ inline void ldsbar(){
  asm volatile("s_waitcnt lgkmcnt(0)" ::: "memory");
  __builtin_amdgcn_s_barrier();
}

// ---------------- conv_w: weight conversions + zero counts/pool ----------------
__global__ void conv_w(const float* __restrict__ w1, const float* __restrict__ wih,
                       const float* __restrict__ whh,
                       short* __restrict__ o1, short* __restrict__ oih, short* __restrict__ ohh,
                       uint8_t* __restrict__ w1q,
                       float* __restrict__ counts, float* __restrict__ pool){
  int i = blockIdx.x * 256 + threadIdx.x;
  if (i < H*H) o1[i] = f2bf(w1[i]);
  if (i < 3*H*H){ oih[i] = f2bf(wih[i]); ohh[i] = f2bf(whh[i]); }
  if (i < H*H/4){
    float4 v = *(const float4*)(w1 + (size_t)i*4);
    *(uint32_t*)(w1q + (size_t)i*4) = pkfp8(v);
  }
  if (i < G) counts[i] = 0.f;
  for (int j = i; j < G*H; j += 768*256) pool[j] = 0.f;
}

// ---------------- K0: mean-pool + counts + write x_fp8 + zero sgate ----------------
__global__ __launch_bounds__(512) __attribute__((amdgpu_waves_per_eu(2, 8)))
void k0_pool(const float* __restrict__ x, const int* __restrict__ batch,
             float* __restrict__ pool, float* __restrict__ counts,
             uint8_t* __restrict__ xq, float* __restrict__ sgate, int nNodes){
  __shared__ int   ng[TP0];
  __shared__ float Pacc[8][H];
  __shared__ float Cacc[8];
  __shared__ int   spanSh;

  const int t = threadIdx.x;
  const int base = blockIdx.x * TP0;
  const int c4 = (t & 63) * 4;
  const int r0 = (t >> 6) * 16;   // 8 row-groups of 16 rows

  float4 v[16];
  #pragma unroll
  for (int i = 0; i < 16; ++i){
    int node = base + r0 + i;
    if (node < nNodes) v[i] = *(const float4*)(x + (size_t)node*H + c4);
    else v[i] = make_float4(0.f,0.f,0.f,0.f);
  }

  { int gi = blockIdx.x * 512 + t; if (gi < nNodes) sgate[gi] = 0.f; }

  if (t < TP0) ng[t] = (base + t < nNodes) ? batch[base + t] : -1;
  for (int u = t; u < 8*H; u += 512) ((float*)Pacc)[u] = 0.f;
  if (t < 8) Cacc[t] = 0.f;
  __syncthreads();

  if (t == 0){
    int lg = ng[0];
    if (base + TP0 <= nNodes) lg = ng[TP0-1];
    else { for (int i = TP0-1; i > 0; --i){ if (ng[i] >= 0){ lg = ng[i]; break; } } }
    spanSh = (ng[0] >= 0) ? (lg - ng[0]) : -1;
  }

  if (xq){
    #pragma unroll
    for (int i = 0; i < 16; ++i){
      int node = base + r0 + i;
      if (node < nNodes)
        *(uint32_t*)(xq + (size_t)node*H + c4) = pkfp8(v[i]);
    }
  }
  __syncthreads();

  const int g0 = ng[0];
  const bool useLds = (spanSh >= 0) && (spanSh < 8);

  float ax=0.f, ay=0.f, az=0.f, aw=0.f;
  int cur = ng[r0];
  if (cur >= 0){
    #pragma unroll
    for (int i = 0; i < 16; ++i){
      int g = ng[r0 + i];
      if (g < 0) break;
      if (g != cur){
        if (useLds){
          atomicAdd(&Pacc[cur-g0][c4], ax);   atomicAdd(&Pacc[cur-g0][c4+1], ay);
          atomicAdd(&Pacc[cur-g0][c4+2], az); atomicAdd(&Pacc[cur-g0][c4+3], aw);
        } else {
          atomicAdd(&pool[(size_t)cur*H + c4], ax);   atomicAdd(&pool[(size_t)cur*H + c4+1], ay);
          atomicAdd(&pool[(size_t)cur*H + c4+2], az); atomicAdd(&pool[(size_t)cur*H + c4+3], aw);
        }
        ax=ay=az=aw=0.f; cur = g;
      }
      ax += v[i].x; ay += v[i].y; az += v[i].z; aw += v[i].w;
    }
    if (useLds){
      atomicAdd(&Pacc[cur-g0][c4], ax);   atomicAdd(&Pacc[cur-g0][c4+1], ay);
      atomicAdd(&Pacc[cur-g0][c4+2], az); atomicAdd(&Pacc[cur-g0][c4+3], aw);
    } else {
      atomicAdd(&pool[(size_t)cur*H + c4], ax);   atomicAdd(&pool[(size_t)cur*H + c4+1], ay);
      atomicAdd(&pool[(size_t)cur*H + c4+2], az); atomicAdd(&pool[(size_t)cur*H + c4+3], aw);
    }
  }
  if (t < TP0 && ng[t] >= 0){
    if (useLds) atomicAdd(&Cacc[ng[t]-g0], 1.f);
    else        atomicAdd(&counts[ng[t]], 1.f);
  }
  __syncthreads();

  if (useLds){
    int nr = spanSh + 1;
    for (int u = t; u < nr*H; u += 512){
      int r = u >> 8, c = u & 255;
      float vv = Pacc[r][c];
      if (vv != 0.f) atomicAdd(&pool[(size_t)(g0+r)*H + c], vv);
    }
    if (t < nr && Cacc[t] != 0.f) atomicAdd(&counts[g0 + t], Cacc[t]);
  }
}

// ---------------- KT2: repr = pool/cnt; zero pool; hgp GEMM ----------------
__global__ __launch_bounds__(256) void kT2(float* __restrict__ pool,
    const float* __restrict__ counts, float* __restrict__ repr,
    const short* __restrict__ w1bf, const float* __restrict__ b1,
    uint32_t* __restrict__ hgp){
  __shared__ short Ar[16][H + 8];
  const int t    = threadIdx.x;
  const int wid  = t >> 6;
  const int lane = t & 63;
  const int l15  = lane & 15;
  const int l4   = lane >> 4;
  const int g0   = blockIdx.x * 16;

  for (int u = t; u < 16*32; u += 256){
    int row = u >> 5, cg = u & 31;
    int c0 = cg * 8;
    int g = g0 + row;
    float cnt = fmaxf(counts[g], 1.f);
    float4* pp = (float4*)(pool + (size_t)g*H + c0);
    float4 p0 = pp[0], p1 = pp[1];
    p0.x/=cnt; p0.y/=cnt; p0.z/=cnt; p0.w/=cnt;
    p1.x/=cnt; p1.y/=cnt; p1.z/=cnt; p1.w/=cnt;
    float4* rp = (float4*)(repr + (size_t)g*H + c0);
    rp[0] = p0; rp[1] = p1;
    pp[0] = make_float4(0.f,0.f,0.f,0.f);
    pp[1] = make_float4(0.f,0.f,0.f,0.f);
    bf16x8 o;
    o[0]=f2bf(p0.x); o[1]=f2bf(p0.y); o[2]=f2bf(p0.z); o[3]=f2bf(p0.w);
    o[4]=f2bf(p1.x); o[5]=f2bf(p1.y); o[6]=f2bf(p1.z); o[7]=f2bf(p1.w);
    *(bf16x8*)(&Ar[row][c0]) = o;
  }
  __syncthreads();

  f32x4 acc[4];
  #pragma unroll
  for (int i = 0; i < 4; ++i) acc[i] = (f32x4){0.f,0.f,0.f,0.f};
  #pragma unroll
  for (int kc = 0; kc < 8; ++kc){
    bf16x8 a = *(bf16x8*)(&Ar[l15][kc*32 + l4*8]);
    #pragma unroll
    for (int nt = 0; nt < 4; ++nt){
      int col = wid*64 + nt*16 + l15;
      bf16x8 b = *(const bf16x8*)(w1bf + (size_t)col*H + kc*32 + l4*8);
      acc[nt] = __builtin_amdgcn_mfma_f32_16x16x32_bf16(a, b, acc[nt], 0, 0, 0);
    }
  }
  const float b1v0 = b1[wid*64 + l15];
  const float b1v1 = b1[wid*64 + 16 + l15];
  const float b1v2 = b1[wid*64 + 32 + l15];
  const float b1v3 = b1[wid*64 + 48 + l15];
  #pragma unroll
  for (int j = 0; j < 4; ++j){
    int row = l4*4 + j;
    hgp[(size_t)(g0+row)*128 + wid*32 + l15]      = pk2(acc[0][j]+b1v0, acc[1][j]+b1v1);
    hgp[(size_t)(g0+row)*128 + wid*32 + 16 + l15] = pk2(acc[2][j]+b1v2, acc[3][j]+b1v3);
  }
}

// ---------------- K1a-fp8: gate scores, FULL-COL persistent GEMM (R17 proven) ----------------
__global__ __launch_bounds__(256) __attribute__((amdgpu_waves_per_eu(3, 4)))
void k1a_fp8(
    const uint8_t* __restrict__ xq, const int* __restrict__ batch,
    const uint32_t* __restrict__ hgp, const uint8_t* __restrict__ w1q,
    const float* __restrict__ w2, float* __restrict__ sgate,
    int nNodes, int nTiles, int nBlk){

  __shared__ uint8_t Ain[2][TK][H + 16];   // 272B pitch, 17.4 KB
  __shared__ int     ngS[2][TK];

  const int t    = threadIdx.x;
  const int wid  = t >> 6;      // 0..3 -> cols wid*64 .. wid*64+64
  const int lane = t & 63;
  const int l15  = lane & 15;
  const int l4   = lane >> 4;
  const int colB = wid*64;

  const int tile0 = (int)(((long long)blockIdx.x * nTiles) / nBlk);
  const int tile1 = (int)(((long long)(blockIdx.x+1) * nTiles) / nBlk);
  if (tile0 >= tile1) return;

  long BfA0[8], BfA1[8], BfB0[8], BfB1[8];
  {
    const uint8_t* wp = w1q + (size_t)(colB + l15)*H + l4*8;
    #pragma unroll
    for (int kc = 0; kc < 8; ++kc){
      BfA0[kc] = *(const long*)(wp + kc*32);
      BfA1[kc] = *(const long*)(wp + 16*H + kc*32);
      BfB0[kc] = *(const long*)(wp + 32*H + kc*32);
      BfB1[kc] = *(const long*)(wp + 48*H + kc*32);
    }
  }
  const float w2A0 = w2[colB + l15];
  const float w2A1 = w2[colB + 16 + l15];
  const float w2B0 = w2[colB + 32 + l15];
  const float w2B1 = w2[colB + 48 + l15];

  const int srow  = t >> 4;        // 0..15
  const int scolB = (t & 15) * 16; // byte offset
  uint4 xv0, xv1;
  int ngv = -1;

  auto issueT = [&](int tile){
    int base = tile * TK;
    int n0 = base + srow, n1 = n0 + 16;
    xv0 = (n0 < nNodes) ? *(const uint4*)(xq + (size_t)n0*H + scolB) : make_uint4(0,0,0,0);
    xv1 = (n1 < nNodes) ? *(const uint4*)(xq + (size_t)n1*H + scolB) : make_uint4(0,0,0,0);
    if (t < TK){
      int node = base + t;
      ngv = (node < nNodes) ? batch[node] : -1;
    }
  };
  auto stageT = [&](int buf){
    *(uint4*)(&Ain[buf][srow][scolB])      = xv0;
    *(uint4*)(&Ain[buf][srow + 16][scolB]) = xv1;
    if (t < TK) ngS[buf][t] = ngv;
  };

  issueT(tile0);
  stageT(0);
  if (tile0 + 1 < tile1) issueT(tile0 + 1);

  int cur = 0;
  for (int tile = tile0; tile < tile1; ++tile, cur ^= 1){
    ldsbar();

    // ---- group A: cols colB..colB+32 ----
    uint32_t hvp[2][4];
    #pragma unroll
    for (int r = 0; r < 2; ++r)
      #pragma unroll
      for (int j = 0; j < 4; ++j){
        int g = ngS[cur][r*16 + l4*4 + j];
        hvp[r][j] = (g >= 0) ? hgp[(size_t)g*128 + wid*32 + l15] : 0u;
      }

    f32x4 acc0[2], acc1[2];
    #pragma unroll
    for (int r = 0; r < 2; ++r){ acc0[r] = (f32x4){0.f,0.f,0.f,0.f}; acc1[r] = (f32x4){0.f,0.f,0.f,0.f}; }
    #pragma unroll
    for (int kc = 0; kc < 8; ++kc){
      #pragma unroll
      for (int r = 0; r < 2; ++r){
        long a = *(const long*)(&Ain[cur][r*16 + l15][kc*32 + l4*8]);
        acc0[r] = __builtin_amdgcn_mfma_f32_16x16x32_fp8_fp8(a, BfA0[kc], acc0[r], 0, 0, 0);
        acc1[r] = __builtin_amdgcn_mfma_f32_16x16x32_fp8_fp8(a, BfA1[kc], acc1[r], 0, 0, 0);
      }
    }

    if (tile + 1 < tile1){
      stageT(cur ^ 1);
      if (tile + 2 < tile1) issueT(tile + 2);
    }

    float p[2][4];
    #pragma unroll
    for (int r = 0; r < 2; ++r)
      #pragma unroll
      for (int j = 0; j < 4; ++j){
        float h0 = fmaxf(acc0[r][j] + bf2f((short)(uint16_t)(hvp[r][j] & 0xFFFFu)), 0.f);
        float h1 = fmaxf(acc1[r][j] + bf2f((short)(uint16_t)(hvp[r][j] >> 16)), 0.f);
        p[r][j] = w2A0*h0 + w2A1*h1;
      }

    // ---- group B: cols colB+32..colB+64 ----
    #pragma unroll
    for (int r = 0; r < 2; ++r)
      #pragma unroll
      for (int j = 0; j < 4; ++j){
        int g = ngS[cur][r*16 + l4*4 + j];
        hvp[r][j] = (g >= 0) ? hgp[(size_t)g*128 + wid*32 + 16 + l15] : 0u;
      }
    #pragma unroll
    for (int r = 0; r < 2; ++r){ acc0[r] = (f32x4){0.f,0.f,0.f,0.f}; acc1[r] = (f32x4){0.f,0.f,0.f,0.f}; }
    #pragma unroll
    for (int kc = 0; kc < 8; ++kc){
      #pragma unroll
      for (int r = 0; r < 2; ++r){
        long a = *(const long*)(&Ain[cur][r*16 + l15][kc*32 + l4*8]);
        acc0[r] = __builtin_amdgcn_mfma_f32_16x16x32_fp8_fp8(a, BfB0[kc], acc0[r], 0, 0, 0);
        acc1[r] = __builtin_amdgcn_mfma_f32_16x16x32_fp8_fp8(a, BfB1[kc], acc1[r], 0, 0, 0);
      }
    }
    #pragma unroll
    for (int r = 0; r < 2; ++r)
      #pragma unroll
      for (int j = 0; j < 4; ++j){
        float h0 = fmaxf(acc0[r][j] + bf2f((short)(uint16_t)(hvp[r][j] & 0xFFFFu)), 0.f);
        float h1 = fmaxf(acc1[r][j] + bf2f((short)(uint16_t)(hvp[r][j] >> 16)), 0.f);
        p[r][j] += w2B0*h0 + w2B1*h1;
      }

    #pragma unroll
    for (int off = 1; off < 16; off <<= 1){
      #pragma unroll
      for (int r = 0; r < 2; ++r)
        #pragma unroll
        for (int j = 0; j < 4; ++j) p[r][j] += __shfl_xor(p[r][j], off);
    }
    if (l15 == 0){
      int base = tile * TK;
      #pragma unroll
      for (int r = 0; r < 2; ++r)
        #pragma unroll
        for (int j = 0; j < 4; ++j){
          int idx = r*16 + l4*4 + j;
          if (ngS[cur][idx] >= 0)
            atomicAdd(&sgate[base + idx], p[r][j]);
        }
    }
  }
}

// ---------------- K1b-q8: streaming pooling from fp8 x, 512-row tiles; zeroes sgate ----------------
__global__ __launch_bounds__(512) __attribute__((amdgpu_waves_per_eu(2, 8)))
void k1b_q8(
    const uint8_t* __restrict__ xq, const int* __restrict__ batch,
    float* __restrict__ sgate, const float* __restrict__ b2p,
    float* __restrict__ pool, int nNodes){

  __shared__ int   ng[TPB];
  __shared__ float gs[TPB];
  __shared__ float Pacc[16][H];
  __shared__ int   spanSh;

  const int t = threadIdx.x;
  const int base = blockIdx.x * TPB;
  const int c4 = (t & 63) * 4;
  const int r0 = (t >> 6) * 64;   // 8 row-groups of 64 rows

  // 64 x 4B = 256 B/thread in flight
  uint32_t u[64];
  #pragma unroll
  for (int i = 0; i < 64; ++i){
    int node = base + r0 + i;
    u[i] = (node < nNodes) ? *(const uint32_t*)(xq + (size_t)node*H + c4) : 0u;
  }

  const float b2v = b2p[0];
  {
    int node = base + t;
    if (node < nNodes){
      ng[t] = batch[node];
      gs[t] = sigmoidf_(sgate[node] + b2v);
      sgate[node] = 0.f;               // ready for next k1a pass
    } else { ng[t] = -1; gs[t] = 0.f; }
  }
  for (int w = t; w < 16*H; w += 512) ((float*)Pacc)[w] = 0.f;
  __syncthreads();

  if (t == 0){
    int lg = ng[0];
    if (base + TPB <= nNodes) lg = ng[TPB-1];
    else { for (int i = TPB-1; i > 0; --i){ if (ng[i] >= 0){ lg = ng[i]; break; } } }
    spanSh = (ng[0] >= 0) ? (lg - ng[0]) : -1;
  }
  __syncthreads();

  const int g0 = ng[0];
  const bool useLds = (spanSh >= 0) && (spanSh < 16);

  float ax=0.f, ay=0.f, az=0.f, aw=0.f;
  int cur = ng[r0];
  if (cur >= 0){
    #pragma unroll
    for (int i = 0; i < 64; ++i){
      int g = ng[r0 + i];
      if (g < 0) break;
      if (g != cur){
        if (useLds){
          atomicAdd(&Pacc[cur-g0][c4], ax);   atomicAdd(&Pacc[cur-g0][c4+1], ay);
          atomicAdd(&Pacc[cur-g0][c4+2], az); atomicAdd(&Pacc[cur-g0][c4+3], aw);
        } else {
          atomicAdd(&pool[(size_t)cur*H + c4], ax);   atomicAdd(&pool[(size_t)cur*H + c4+1], ay);
          atomicAdd(&pool[(size_t)cur*H + c4+2], az); atomicAdd(&pool[(size_t)cur*H + c4+3], aw);
        }
        ax=ay=az=aw=0.f; cur = g;
      }
      float gv = gs[r0 + i];
      f32x2 lo = __builtin_amdgcn_cvt_pk_f32_fp8((int)u[i], false);
      f32x2 hi = __builtin_amdgcn_cvt_pk_f32_fp8((int)u[i], true);
      ax += gv * lo[0]; ay += gv * lo[1];
      az += gv * hi[0]; aw += gv * hi[1];
    }
    if (useLds){
      atomicAdd(&Pacc[cur-g0][c4], ax);   atomicAdd(&Pacc[cur-g0][c4+1], ay);
      atomicAdd(&Pacc[cur-g0][c4+2], az); atomicAdd(&Pacc[cur-g0][c4+3], aw);
    } else {
      atomicAdd(&pool[(size_t)cur*H + c4], ax);   atomicAdd(&pool[(size_t)cur*H + c4+1], ay);
      atomicAdd(&pool[(size_t)cur*H + c4+2], az); atomicAdd(&pool[(size_t)cur*H + c4+3], aw);
    }
  }
  __syncthreads();

  if (useLds){
    int nr = spanSh + 1;
    for (int w = t; w < nr*H; w += 512){
      int r = w >> 8, c = w & 255;
      float vv = Pacc[r][c];
      if (vv != 0.f) atomicAdd(&pool[(size_t)(g0+r)*H + c], vv);
    }
  }
}

// ---------------- fallback path (small ws): bf16 col-half GEMM + f32 pooling ----------------
__global__ __launch_bounds__(256) __attribute__((amdgpu_waves_per_eu(3, 4)))
void k1a_gate_f32(
    const float* __restrict__ xf32, const int* __restrict__ batch,
    const uint32_t* __restrict__ hgp, const short* __restrict__ w1bf,
    const float* __restrict__ w2, float* __restrict__ sgate,
    int nNodes, int nTiles, int nChains){

  __shared__ short Ain[2][TK][H + 8];
  __shared__ int   ngS[2][TK];

  const int t    = threadIdx.x;
  const int wid  = t >> 6;
  const int lane = t & 63;
  const int l15  = lane & 15;
  const int l4   = lane >> 4;

  const int ch    = blockIdx.x >= nChains;
  const int chain = ch ? blockIdx.x - nChains : blockIdx.x;
  const int colB  = ch*128 + wid*32;
  const int hgcol = ch*64 + wid*16 + l15;

  const int tile0 = (int)(((long long)chain * nTiles) / nChains);
  const int tile1 = (int)(((long long)(chain+1) * nTiles) / nChains);
  if (tile0 >= tile1) return;

  bf16x8 Bf0[8], Bf1[8];
  {
    const short* wp0 = w1bf + (size_t)(colB + l15)*H + l4*8;
    #pragma unroll
    for (int kc = 0; kc < 8; ++kc){
      Bf0[kc] = *(const bf16x8*)(wp0 + kc*32);
      Bf1[kc] = *(const bf16x8*)(wp0 + 16*H + kc*32);
    }
  }
  const float w2v0 = w2[colB + l15];
  const float w2v1 = w2[colB + 16 + l15];

  const int srow = t >> 5;
  const int scol = (t & 31) * 8;
  float4 xf[4][2];
  int ngv = -1;

  auto issueT = [&](int tile){
    int base = tile * TK;
    #pragma unroll
    for (int q = 0; q < 4; ++q){
      int node = base + srow + q*8;
      if (node < nNodes){
        const float4* xp = (const float4*)(xf32 + (size_t)node*H + scol);
        xf[q][0] = xp[0]; xf[q][1] = xp[1];
      } else { xf[q][0] = make_float4(0.f,0.f,0.f,0.f); xf[q][1] = make_float4(0.f,0.f,0.f,0.f); }
    }
    if (t < TK){
      int node = base + t;
      ngv = (node < nNodes) ? batch[node] : -1;
    }
  };
  auto stageT = [&](int buf){
    #pragma unroll
    for (int q = 0; q < 4; ++q){
      bf16x8 o;
      float4 a = xf[q][0], c = xf[q][1];
      o[0]=f2bf(a.x); o[1]=f2bf(a.y); o[2]=f2bf(a.z); o[3]=f2bf(a.w);
      o[4]=f2bf(c.x); o[5]=f2bf(c.y); o[6]=f2bf(c.z); o[7]=f2bf(c.w);
      *(bf16x8*)(&Ain[buf][srow + q*8][scol]) = o;
    }
    if (t < TK) ngS[buf][t] = ngv;
  };

  issueT(tile0);
  stageT(0);
  if (tile0 + 1 < tile1) issueT(tile0 + 1);

  int cur = 0;
  for (int tile = tile0; tile < tile1; ++tile, cur ^= 1){
    ldsbar();

    int gr[2][4];
    uint32_t hvp[2][4];
    #pragma unroll
    for (int r = 0; r < 2; ++r)
      #pragma unroll
      for (int j = 0; j < 4; ++j){
        int g = ngS[cur][r*16 + l4*4 + j];
        gr[r][j] = g;
        hvp[r][j] = (g >= 0) ? hgp[(size_t)g*128 + hgcol] : 0u;
      }

    f32x4 acc0[2], acc1[2];
    #pragma unroll
    for (int r = 0; r < 2; ++r){ acc0[r] = (f32x4){0.f,0.f,0.f,0.f}; acc1[r] = (f32x4){0.f,0.f,0.f,0.f}; }
    #pragma unroll
    for (int kc = 0; kc < 8; ++kc){
      #pragma unroll
      for (int r = 0; r < 2; ++r){
        bf16x8 a = *(bf16x8*)(&Ain[cur][r*16 + l15][kc*32 + l4*8]);
        acc0[r] = __builtin_amdgcn_mfma_f32_16x16x32_bf16(a, Bf0[kc], acc0[r], 0, 0, 0);
        acc1[r] = __builtin_amdgcn_mfma_f32_16x16x32_bf16(a, Bf1[kc], acc1[r], 0, 0, 0);
      }
    }

    if (tile + 1 < tile1){
      stageT(cur ^ 1);
      if (tile + 2 < tile1) issueT(tile + 2);
    }

    float p[2][4];
    #pragma unroll
    for (int r = 0; r < 2; ++r)
      #pragma unroll
      for (int j = 0; j < 4; ++j){
        float h0 = fmaxf(acc0[r][j] + bf2f((short)(uint16_t)(hvp[r][j] & 0xFFFFu)), 0.f);
        float h1 = fmaxf(acc1[r][j] + bf2f((short)(uint16_t)(hvp[r][j] >> 16)), 0.f);
        p[r][j] = w2v0*h0 + w2v1*h1;
      }
    #pragma unroll
    for (int off = 1; off < 16; off <<= 1){
      #pragma unroll
      for (int r = 0; r < 2; ++r)
        #pragma unroll
        for (int j = 0; j < 4; ++j) p[r][j] += __shfl_xor(p[r][j], off);
    }
    if (l15 == 0){
      int base = tile * TK;
      #pragma unroll
      for (int r = 0; r < 2; ++r)
        #pragma unroll
        for (int j = 0; j < 4; ++j){
          if (gr[r][j] >= 0)
            atomicAdd(&sgate[base + r*16 + l4*4 + j], p[r][j]);
        }
    }
  }
}

__global__ __launch_bounds__(512) __attribute__((amdgpu_waves_per_eu(2, 8)))
void k1b_f32(
    const float* __restrict__ xf32, const int* __restrict__ batch,
    float* __restrict__ sgate, const float* __restrict__ b2p,
    float* __restrict__ pool, int nNodes){

  __shared__ int   ng[TP0];
  __shared__ float gs[TP0];
  __shared__ float Pacc[8][H];
  __shared__ int   spanSh;

  const int t = threadIdx.x;
  const int base = blockIdx.x * TP0;
  const int c4 = (t & 63) * 4;
  const int r0 = (t >> 6) * 16;

  float4 vf[16];
  #pragma unroll
  for (int i = 0; i < 16; ++i){
    int node = base + r0 + i;
    vf[i] = (node < nNodes) ? *(const float4*)(xf32 + (size_t)node*H + c4)
                            : make_float4(0.f,0.f,0.f,0.f);
  }

  const float b2v = b2p[0];
  if (t < TP0){
    int node = base + t;
    if (node < nNodes){
      ng[t] = batch[node];
      gs[t] = sigmoidf_(sgate[node] + b2v);
      sgate[node] = 0.f;
    } else { ng[t] = -1; gs[t] = 0.f; }
  }
  for (int w = t; w < 8*H; w += 512) ((float*)Pacc)[w] = 0.f;
  __syncthreads();

  if (t == 0){
    int lg = ng[0];
    if (base + TP0 <= nNodes) lg = ng[TP0-1];
    else { for (int i = TP0-1; i > 0; --i){ if (ng[i] >= 0){ lg = ng[i]; break; } } }
    spanSh = (ng[0] >= 0) ? (lg - ng[0]) : -1;
  }
  __syncthreads();

  const int g0 = ng[0];
  const bool useLds = (spanSh >= 0) && (spanSh < 8);

  float ax=0.f, ay=0.f, az=0.f, aw=0.f;
  int cur = ng[r0];
  if (cur >= 0){
    #pragma unroll
    for (int i = 0; i < 16; ++i){
      int g = ng[r0 + i];
      if (g < 0) break;
      if (g != cur){
        if (useLds){
          atomicAdd(&Pacc[cur-g0][c4], ax);   atomicAdd(&Pacc[cur-g0][c4+1], ay);
          atomicAdd(&Pacc[cur-g0][c4+2], az); atomicAdd(&Pacc[cur-g0][c4+3], aw);
        } else {
          atomicAdd(&pool[(size_t)cur*H + c4], ax);   atomicAdd(&pool[(size_t)cur*H + c4+1], ay);
          atomicAdd(&pool[(size_t)cur*H + c4+2], az); atomicAdd(&pool[(size_t)cur*H + c4+3], aw);
        }
        ax=ay=az=aw=0.f; cur = g;
      }
      float gv = gs[r0 + i];
      ax += gv * bf2f(f2bf(vf[i].x)); ay += gv * bf2f(f2bf(vf[i].y));
      az += gv * bf2f(f2bf(vf[i].z)); aw += gv * bf2f(f2bf(vf[i].w));
    }
    if (useLds){
      atomicAdd(&Pacc[cur-g0][c4], ax);   atomicAdd(&Pacc[cur-g0][c4+1], ay);
      atomicAdd(&Pacc[cur-g0][c4+2], az); atomicAdd(&Pacc[cur-g0][c4+3], aw);
    } else {
      atomicAdd(&pool[(size_t)cur*H + c4], ax);   atomicAdd(&pool[(size_t)cur*H + c4+1], ay);
      atomicAdd(&pool[(size_t)cur*H + c4+2], az); atomicAdd(&pool[(size_t)cur*H + c4+3], aw);
    }
  }
  __syncthreads();

  if (useLds){
    int nr = spanSh + 1;
    for (int w = t; w < nr*H; w += 512){
      int r = w >> 8, c = w & 255;
      float vv = Pacc[r][c];
      if (vv != 0.f) atomicAdd(&pool[(size_t)(g0+r)*H + c], vv);
    }
  }
}

// ---------------- K2: fused GRU (+ optional hgp for next ts); zeroes pool ----------------
__global__ __launch_bounds__(256) void k2_gru(float* __restrict__ pool,
    const float* __restrict__ counts, const float* __restrict__ repr_in,
    const short* __restrict__ wihbf, const short* __restrict__ whhbf,
    const float* __restrict__ bih, const float* __restrict__ bhh,
    float* __restrict__ repr_out,
    const short* __restrict__ w1bf, const float* __restrict__ b1,
    uint32_t* __restrict__ hgp, int doHg){

  __shared__ short Anew[16][H + 8];
  __shared__ short Aold[16][H + 8];
  __shared__ float hold[16][H];
  __shared__ float srz[16][2*H];
  __shared__ float sni[16][H];
  __shared__ float snh[16][H];

  const int t    = threadIdx.x;
  const int wid  = t >> 6;
  const int lane = t & 63;
  const int l15  = lane & 15;
  const int l4   = lane >> 4;
  const int g0   = blockIdx.x * 16;

  for (int u = t; u < 16*H; u += 256){
    int row = u >> 8, c = u & 255;
    int g = g0 + row;
    float cnt = fmaxf(counts[g], 1.f);
    float rin = repr_in[(size_t)g*H + c];
    float nr  = pool[(size_t)g*H + c] / cnt;
    pool[(size_t)g*H + c] = 0.f;
    Anew[row][c] = f2bf(nr);
    Aold[row][c] = f2bf(rin);
    hold[row][c] = rin;
  }
  __syncthreads();

  f32x4 ai[12], ah[12];
  #pragma unroll
  for (int i = 0; i < 12; ++i){ ai[i] = (f32x4){0.f,0.f,0.f,0.f}; ah[i] = (f32x4){0.f,0.f,0.f,0.f}; }

  for (int kc = 0; kc < 8; ++kc){
    bf16x8 an = *(bf16x8*)(&Anew[l15][kc*32 + l4*8]);
    bf16x8 ao = *(bf16x8*)(&Aold[l15][kc*32 + l4*8]);
    #pragma unroll
    for (int nt = 0; nt < 12; ++nt){
      int n = wid*192 + nt*16 + l15;
      bf16x8 bi = *(const bf16x8*)(wihbf + (size_t)n*H + kc*32 + l4*8);
      bf16x8 bh = *(const bf16x8*)(whhbf + (size_t)n*H + kc*32 + l4*8);
      ai[nt] = __builtin_amdgcn_mfma_f32_16x16x32_bf16(an, bi, ai[nt], 0, 0, 0);
      ah[nt] = __builtin_amdgcn_mfma_f32_16x16x32_bf16(ao, bh, ah[nt], 0, 0, 0);
    }
  }

  #pragma unroll
  for (int nt = 0; nt < 12; ++nt){
    int n = wid*192 + nt*16 + l15;
    float bi = bih[n], bh = bhh[n];
    #pragma unroll
    for (int r = 0; r < 4; ++r){
      int row = l4*4 + r;
      float si = ai[nt][r] + bi;
      float sh = ah[nt][r] + bh;
      if (n < 2*H) srz[row][n] = si + sh;
      else { sni[row][n - 2*H] = si; snh[row][n - 2*H] = sh; }
    }
  }
  __syncthreads();

  for (int u = t; u < 16*H; u += 256){
    int row = u >> 8, c = u & 255;
    float rr = sigmoidf_(srz[row][c]);
    float zz = sigmoidf_(srz[row][H + c]);
    float nn = tanhf(sni[row][c] + rr * snh[row][c]);
    float hv = (1.f - zz) * nn + zz * hold[row][c];
    float out = fmaxf(hv, 0.f);
    repr_out[(size_t)(g0 + row)*H + c] = out;
    Anew[row][c] = f2bf(out);
  }

  if (doHg){
    __syncthreads();
    f32x4 acc[4];
    #pragma unroll
    for (int i = 0; i < 4; ++i) acc[i] = (f32x4){0.f,0.f,0.f,0.f};
    #pragma unroll
    for (int kc = 0; kc < 8; ++kc){
      bf16x8 a = *(bf16x8*)(&Anew[l15][kc*32 + l4*8]);
      #pragma unroll
      for (int nt = 0; nt < 4; ++nt){
        int col = wid*64 + nt*16 + l15;
        bf16x8 b = *(const bf16x8*)(w1bf + (size_t)col*H + kc*32 + l4*8);
        acc[nt] = __builtin_amdgcn_mfma_f32_16x16x32_bf16(a, b, acc[nt], 0, 0, 0);
      }
    }
    const float b1v0 = b1[wid*64 + l15];
    const float b1v1 = b1[wid*64 + 16 + l15];
    const float b1v2 = b1[wid*64 + 32 + l15];
    const float b1v3 = b1[wid*64 + 48 + l15];
    #pragma unroll
    for (int j = 0; j < 4; ++j){
      int row = l4*4 + j;
      hgp[(size_t)(g0+row)*128 + wid*32 + l15]      = pk2(acc[0][j]+b1v0, acc[1][j]+b1v1);
      hgp[(size_t)(g0+row)*128 + wid*32 + 16 + l15] = pk2(acc[2][j]+b1v2, acc[3][j]+b1v3);
    }
  }
}

extern "C" void kernel_launch(void* const* d_in, const int* in_sizes, int n_in,
                              void* d_out, int out_size, void* d_ws, size_t ws_size,
                              hipStream_t stream){
  const float* x    = (const float*)d_in[0];
  const float* w1   = (const float*)d_in[1];
  const float* b1   = (const float*)d_in[2];
  const float* w2   = (const float*)d_in[3];
  const float* b2   = (const float*)d_in[4];
  const float* wih  = (const float*)d_in[5];
  const float* whh  = (const float*)d_in[6];
  const float* bih  = (const float*)d_in[7];
  const float* bhh  = (const float*)d_in[8];
  const int*   batch= (const int*)d_in[9];
  const int N = in_sizes[9];

  char* ws = (char*)d_ws;
  short* w1bf   = (short*)(ws + 0);            // 128 KB
  short* wihbf  = (short*)(ws + (1u<<17));     // 384 KB @128K
  short* whhbf  = (short*)(ws + (1u<<19));     // 384 KB @512K
  float* counts = (float*)(ws + 917504);       // 16 KB @896K
  uint8_t* w1q  = (uint8_t*)(ws + 933888);     // 64 KB @912K
  float* pool   = (float*)(ws + (1u<<20));     // 4 MB @1M
  float* repr   = (float*)(ws + (1u<<20) + (1u<<22)); // 4 MB @5M
  float* sgate  = (float*)(ws + (9u<<20));     // 2 MB @9M
  uint32_t* hgp = (uint32_t*)(ws + (12u<<20)); // 2 MB @12M
  float* outp   = (float*)d_out;

  const size_t XQ_OFF = (size_t)16u << 20;     // 16 MB
  const bool useXq = ws_size >= XQ_OFF + (size_t)N * H;  // xq = 128 MB
  uint8_t* xq = useXq ? (uint8_t*)(ws + XQ_OFF) : nullptr;

  const int nTiles32 = (N + TK - 1) / TK;      // 15625
  const int nBlk1a  = 1024;                    // full-col fp8: 4 blocks/CU
  const int nChainsF= 512;                     // fallback bf16 col-half grid
  const int nBlkP   = (N + TP0 - 1) / TP0;     // 3907 (k0, fallback k1b)
  const int nBlkQ   = (N + TPB - 1) / TPB;     // 977 (k1b_q8)

  conv_w<<<768, 256, 0, stream>>>(w1, wih, whh, w1bf, wihbf, whhbf, w1q, counts, pool);
  k0_pool<<<nBlkP, 512, 0, stream>>>(x, batch, pool, counts, xq, sgate, N);
  kT2<<<G/16, 256, 0, stream>>>(pool, counts, repr, w1bf, b1, hgp);

  for (int ts = 0; ts < 2; ++ts){
    if (useXq){
      k1a_fp8<<<nBlk1a, 256, 0, stream>>>(xq, batch, hgp, w1q, w2, sgate, N, nTiles32, nBlk1a);
      k1b_q8<<<nBlkQ, 512, 0, stream>>>(xq, batch, sgate, b2, pool, N);
    } else {
      k1a_gate_f32<<<nChainsF*2, 256, 0, stream>>>(x, batch, hgp, w1bf, w2, sgate, N, nTiles32, nChainsF);
      k1b_f32<<<nBlkP, 512, 0, stream>>>(x, batch, sgate, b2, pool, N);
    }
    k2_gru<<<G/16, 256, 0, stream>>>(pool, counts, repr, wihbf, whhbf, bih, bhh,
                                     (ts == 0) ? repr : outp,
                                     w1bf, b1, hgp, (ts == 0) ? 1 : 0);
  }
}